// Round 5
// baseline (389.355 us; speedup 1.0000x reference)
//
#include <hip/hip_runtime.h>
#include <hip/hip_bf16.h>

#define DIN 512
#define HID 512

#define AS1 __attribute__((address_space(1)))
#define AS3 __attribute__((address_space(3)))

typedef __attribute__((ext_vector_type(8))) short bfrag;     // 8 bf16 (4 VGPRs)
typedef __attribute__((ext_vector_type(4))) float ffrag;     // 4 fp32 acc
typedef __attribute__((ext_vector_type(4))) unsigned short u16x4;

// ---------------------------------------------------------------------------
// Prelude: transpose+cvt both weight matrices AND count incoming edges.
// ---------------------------------------------------------------------------
__global__ __launch_bounds__(256) void prelude(const float* __restrict__ W1,
                                               const float* __restrict__ W2,
                                               unsigned short* __restrict__ Wt1,
                                               unsigned short* __restrict__ Wt2,
                                               const int* __restrict__ dst,
                                               int* __restrict__ cnt, int E) {
    int b = blockIdx.x;
    if (b < 512) {
        int which = b >> 8;
        int bb = b & 255;
        const float* W = which ? W2 : W1;
        unsigned short* Wt = which ? Wt2 : Wt1;
        __shared__ float t[32][33];
        int tid = threadIdx.x;
        int tx = tid & 31, ty = tid >> 5;          // 32 x 8
        int n0 = (bb & 15) * 32, k0 = (bb >> 4) * 32;
#pragma unroll
        for (int s = 0; s < 4; ++s)
            t[ty + 8 * s][tx] = W[(size_t)(k0 + ty + 8 * s) * 512 + n0 + tx];
        __syncthreads();
#pragma unroll
        for (int s = 0; s < 4; ++s) {
            __hip_bfloat16 v = __float2bfloat16(t[tx][ty + 8 * s]);
            Wt[(size_t)(n0 + ty + 8 * s) * 512 + k0 + tx] = *(unsigned short*)&v;
        }
    } else {
        int e = (b - 512) * 256 + threadIdx.x;
        if (e < E) atomicAdd(&cnt[dst[e]], 1);
    }
}

// ---------------------------------------------------------------------------
// 3-stage scan
// ---------------------------------------------------------------------------
__global__ __launch_bounds__(256) void scan1(const int* __restrict__ cnt, int* __restrict__ tmp,
                                             int* __restrict__ bsum, int N) {
    int tid = threadIdx.x, lane = tid & 63, wave = tid >> 6;
    int i = blockIdx.x * 256 + tid;
    int v = (i < N) ? cnt[i] : 0;
    int incl = v;
#pragma unroll
    for (int o = 1; o < 64; o <<= 1) {
        int t = __shfl_up(incl, o);
        if (lane >= o) incl += t;
    }
    __shared__ int wtot[4];
    if (lane == 63) wtot[wave] = incl;
    __syncthreads();
    int woff = 0;
#pragma unroll
    for (int w = 0; w < 4; ++w) woff += (w < wave) ? wtot[w] : 0;
    if (i < N) tmp[i] = woff + incl - v;
    if (tid == 255) bsum[blockIdx.x] = woff + incl;
}

__global__ void scan2(int* __restrict__ bsum, int nb) {
    int tid = threadIdx.x;  // 128 threads, nb <= 128
    int lane = tid & 63, wave = tid >> 6;
    int v = (tid < nb) ? bsum[tid] : 0;
    int incl = v;
#pragma unroll
    for (int o = 1; o < 64; o <<= 1) {
        int t = __shfl_up(incl, o);
        if (lane >= o) incl += t;
    }
    __shared__ int w0;
    if (tid == 63) w0 = incl;
    __syncthreads();
    int off = wave ? w0 : 0;
    if (tid < nb) bsum[tid] = off + incl - v;
    if (tid == 127) bsum[nb] = off + incl;
}

// offs, cursor(=offs), dis, and d_out bias-init (heads atomicAdd onto it)
__global__ void scan3(const int* __restrict__ cnt, const int* __restrict__ tmp,
                      const int* __restrict__ bsum, int* __restrict__ offs,
                      int* __restrict__ cursor, float* __restrict__ dis,
                      float* __restrict__ out, const float* __restrict__ bo,
                      const float* __restrict__ bw, int N, int nb) {
    int i = blockIdx.x * 256 + threadIdx.x;
    if (i < N) {
        int o = tmp[i] + bsum[i >> 8];
        offs[i] = o;
        cursor[i] = o;
        dis[i] = rsqrtf((float)cnt[i] + 1.0f);
        out[i] = bo[0];
        out[N + i] = bw[0];
    }
    if (i == 0) offs[N] = bsum[nb];
}

// fill CSR as packed records {src, dis[src]}
__global__ void fill_kernel(const int* __restrict__ src, const int* __restrict__ dst,
                            int* __restrict__ cursor, const float* __restrict__ dis,
                            int2* __restrict__ csr2, int E) {
    int e = blockIdx.x * 256 + threadIdx.x;
    if (e >= E) return;
    int d = dst[e];
    int s = src[e];
    int pos = atomicAdd(&cursor[d], 1);
    int2 rec;
    rec.x = s;
    rec.y = __float_as_int(dis[s]);
    csr2[pos] = rec;
}

// ---------------------------------------------------------------------------
// XCD-swizzled tile mapping: b&7 = XCD; per-XCD index covers all 4 n-tiles of
// an m-tile consecutively so the A-tile stays in that XCD's L2.
// ---------------------------------------------------------------------------
__device__ inline bool tile_map(int b, int Mtiles, int& m0, int& n0) {
    int xcd = b & 7, i = b >> 3;
    int nt = i & 3, mg = i >> 2;
    int mt = mg * 8 + xcd;
    if (mt >= Mtiles) return false;
    m0 = mt * 128;
    n0 = nt * 128;
    return true;
}

__device__ inline bfrag pack8(float4 a, float4 b) {
    bfrag o;
    __hip_bfloat16 t;
    t = __float2bfloat16(a.x); o[0] = *(short*)&t;
    t = __float2bfloat16(a.y); o[1] = *(short*)&t;
    t = __float2bfloat16(a.z); o[2] = *(short*)&t;
    t = __float2bfloat16(a.w); o[3] = *(short*)&t;
    t = __float2bfloat16(b.x); o[4] = *(short*)&t;
    t = __float2bfloat16(b.y); o[5] = *(short*)&t;
    t = __float2bfloat16(b.z); o[6] = *(short*)&t;
    t = __float2bfloat16(b.w); o[7] = *(short*)&t;
    return o;
}

// Layer-1 GEMM: fp32 A staged to LDS, cvt at fragment read.
__global__ __launch_bounds__(256) void gemm_a32(const float* __restrict__ A,
                                                const short* __restrict__ B,
                                                unsigned short* __restrict__ C,
                                                int Nvalid, int Mtiles) {
    __shared__ __align__(16) float Asf[128 * 64];  // 32 KB fp32, XOR-16 chunks
    __shared__ __align__(16) short Bs[128 * 64];   // 16 KB bf16, XOR-8 chunks
    const int K = 512;
    int m0, n0;
    if (!tile_map(blockIdx.x, Mtiles, m0, n0)) return;
    int tid = threadIdx.x;
    int lane = tid & 63, wave = tid >> 6;
    int wm = (wave & 1) * 64;
    int wn = (wave >> 1) * 64;
    int r = lane & 15, q = lane >> 4;

    unsigned aoff[8]; int aldso[8];
#pragma unroll
    for (int i = 0; i < 8; ++i) {
        int s = i * 256 + tid;
        int row = s >> 4;
        int c = (s & 15) ^ (row & 15);
        int gr = m0 + row;
        if (gr > Nvalid - 1) gr = Nvalid - 1;
        aoff[i] = (unsigned)gr * K + c * 4;
        aldso[i] = (i * 256 + (tid & ~63)) * 4;
    }
    unsigned boff[4]; int bldso[4];
#pragma unroll
    for (int i = 0; i < 4; ++i) {
        int s = i * 256 + tid;
        int row = s >> 3;
        int c = (s & 7) ^ (row & 7);
        boff[i] = (unsigned)(n0 + row) * K + c * 8;
        bldso[i] = (i * 256 + (tid & ~63)) * 8;
    }

    ffrag acc[4][4];
#pragma unroll
    for (int i = 0; i < 4; ++i)
#pragma unroll
        for (int j = 0; j < 4; ++j) acc[i][j] = ffrag{0.f, 0.f, 0.f, 0.f};

    for (int k0 = 0; k0 < K; k0 += 64) {
#pragma unroll
        for (int i = 0; i < 8; ++i)
            __builtin_amdgcn_global_load_lds((const AS1 void*)(A + aoff[i] + k0),
                                             (AS3 void*)(Asf + aldso[i]), 16, 0, 0);
#pragma unroll
        for (int i = 0; i < 4; ++i)
            __builtin_amdgcn_global_load_lds((const AS1 void*)(B + boff[i] + k0),
                                             (AS3 void*)(Bs + bldso[i]), 16, 0, 0);
        __syncthreads();

#pragma unroll
        for (int s2 = 0; s2 < 2; ++s2) {
            bfrag af[4], bfr[4];
#pragma unroll
            for (int i = 0; i < 4; ++i) {
                int m = wm + i * 16 + r;
                int c0 = s2 * 8 + q * 2;
                int p0 = (c0 ^ (m & 15)) * 4;
                int p1 = ((c0 + 1) ^ (m & 15)) * 4;
                float4 f0 = *(const float4*)&Asf[m * 64 + p0];
                float4 f1 = *(const float4*)&Asf[m * 64 + p1];
                af[i] = pack8(f0, f1);
                int brow = wn + i * 16 + r;
                int bch = (s2 * 4 + q) ^ (brow & 7);
                bfr[i] = *(const bfrag*)&Bs[brow * 64 + bch * 8];
            }
#pragma unroll
            for (int i = 0; i < 4; ++i)
#pragma unroll
                for (int j = 0; j < 4; ++j)
                    acc[i][j] = __builtin_amdgcn_mfma_f32_16x16x32_bf16(bfr[j], af[i], acc[i][j], 0, 0, 0);
        }
        __syncthreads();
    }

#pragma unroll
    for (int i = 0; i < 4; ++i) {
        int m = m0 + wm + i * 16 + r;
#pragma unroll
        for (int j = 0; j < 4; ++j) {
            int n = n0 + wn + j * 16 + q * 4;
            u16x4 o;
#pragma unroll
            for (int reg = 0; reg < 4; ++reg) {
                __hip_bfloat16 v = __float2bfloat16(acc[i][j][reg]);
                o[reg] = *(unsigned short*)&v;
            }
            *(u16x4*)&C[(size_t)m * 512 + n] = o;
        }
    }
}

// Layer-2 GEMM (bf16 A), same swizzle.
__global__ __launch_bounds__(256) void gemm_bf16(const short* __restrict__ A,
                                                 const short* __restrict__ B,
                                                 unsigned short* __restrict__ C,
                                                 int Mtiles) {
    __shared__ __align__(16) short As[128 * 64];
    __shared__ __align__(16) short Bs[128 * 64];
    const int K = 512;
    int m0, n0;
    if (!tile_map(blockIdx.x, Mtiles, m0, n0)) return;
    int tid = threadIdx.x;
    int lane = tid & 63, wave = tid >> 6;
    int wm = (wave & 1) * 64;
    int wn = (wave >> 1) * 64;
    int r = lane & 15, q = lane >> 4;

    unsigned aoff[4], boff[4]; int ldso[4];
#pragma unroll
    for (int i = 0; i < 4; ++i) {
        int s = i * 256 + tid;
        int row = s >> 3;
        int c = (s & 7) ^ (row & 7);
        aoff[i] = (unsigned)(m0 + row) * K + c * 8;
        boff[i] = (unsigned)(n0 + row) * K + c * 8;
        ldso[i] = (i * 256 + (tid & ~63)) * 8;
    }

    ffrag acc[4][4];
#pragma unroll
    for (int i = 0; i < 4; ++i)
#pragma unroll
        for (int j = 0; j < 4; ++j) acc[i][j] = ffrag{0.f, 0.f, 0.f, 0.f};

    for (int k0 = 0; k0 < K; k0 += 64) {
#pragma unroll
        for (int i = 0; i < 4; ++i) {
            __builtin_amdgcn_global_load_lds((const AS1 void*)(A + aoff[i] + k0),
                                             (AS3 void*)(As + ldso[i]), 16, 0, 0);
            __builtin_amdgcn_global_load_lds((const AS1 void*)(B + boff[i] + k0),
                                             (AS3 void*)(Bs + ldso[i]), 16, 0, 0);
        }
        __syncthreads();

#pragma unroll
        for (int s2 = 0; s2 < 2; ++s2) {
            bfrag af[4], bfr[4];
#pragma unroll
            for (int i = 0; i < 4; ++i) {
                int arow = wm + i * 16 + r;
                int ach = (s2 * 4 + q) ^ (arow & 7);
                af[i] = *(const bfrag*)&As[arow * 64 + ach * 8];
                int brow = wn + i * 16 + r;
                int bch = (s2 * 4 + q) ^ (brow & 7);
                bfr[i] = *(const bfrag*)&Bs[brow * 64 + bch * 8];
            }
#pragma unroll
            for (int i = 0; i < 4; ++i)
#pragma unroll
                for (int j = 0; j < 4; ++j)
                    acc[i][j] = __builtin_amdgcn_mfma_f32_16x16x32_bf16(bfr[j], af[i], acc[i][j], 0, 0, 0);
        }
        __syncthreads();
    }

#pragma unroll
    for (int i = 0; i < 4; ++i) {
        int m = m0 + wm + i * 16 + r;
#pragma unroll
        for (int j = 0; j < 4; ++j) {
            int n = n0 + wn + j * 16 + q * 4;
            u16x4 o;
#pragma unroll
            for (int reg = 0; reg < 4; ++reg) {
                __hip_bfloat16 v = __float2bfloat16(acc[i][j][reg]);
                o[reg] = *(unsigned short*)&v;
            }
            *(u16x4*)&C[(size_t)m * 512 + n] = o;
        }
    }
}

// ---------------------------------------------------------------------------
// XCD-sharded aggregation: shard = blockIdx&7 (one XCD) handles 64 channels
// for all nodes -> per-XCD gather footprint 3.2 MB, fits 4 MB L2.
// wave = 1 node, lane = 1 channel. batch-8 edge gathers.
// ---------------------------------------------------------------------------
__global__ __launch_bounds__(256) void agg_relu_sh(const unsigned short* __restrict__ hw,
                                                   const int2* __restrict__ csr2,
                                                   const int* __restrict__ offs,
                                                   const float* __restrict__ dis,
                                                   const float* __restrict__ bias,
                                                   unsigned short* __restrict__ out,
                                                   int N, int Mpad) {
    int b = blockIdx.x;
    int shard = b & 7;
    int node = (b >> 3) * 4 + (threadIdx.x >> 6);
    int lane = threadIdx.x & 63;
    int c = shard * 64 + lane;
    if (node >= N) {
        if (node < Mpad) out[(size_t)node * HID + c] = 0;   // zero pad rows
        return;
    }

    float dn = dis[node];
    int e0 = offs[node], e1 = offs[node + 1];

    float acc;
    {
        unsigned short sv = hw[(size_t)node * HID + c];
        float g = __uint_as_float((unsigned)sv << 16);
        acc = g * dn * dn + bias[c];
    }

    for (int e = e0; e < e1; e += 8) {
        int idx[8]; float wgt[8];
#pragma unroll
        for (int j = 0; j < 8; ++j) {
            int ee = e + j;
            int ec = (ee < e1) ? ee : (e1 - 1);
            int2 rec = csr2[ec];
            idx[j] = rec.x;
            wgt[j] = (ee < e1) ? __int_as_float(rec.y) * dn : 0.f;
        }
        unsigned short v[8];
#pragma unroll
        for (int j = 0; j < 8; ++j)
            v[j] = hw[(size_t)idx[j] * HID + c];
#pragma unroll
        for (int j = 0; j < 8; ++j)
            acc += __uint_as_float((unsigned)v[j] << 16) * wgt[j];
    }

    __hip_bfloat16 o = __float2bfloat16(fmaxf(acc, 0.f));
    out[(size_t)node * HID + c] = *(unsigned short*)&o;
}

// Layer-2 sharded aggregation with fused heads: per-shard 64-ch partial dot,
// wave-reduce, atomicAdd into bias-initialized d_out.
__global__ __launch_bounds__(256) void agg_heads_sh(const unsigned short* __restrict__ hw,
                                                    const int2* __restrict__ csr2,
                                                    const int* __restrict__ offs,
                                                    const float* __restrict__ dis,
                                                    const float* __restrict__ bias,
                                                    const float* __restrict__ Wo,
                                                    const float* __restrict__ Ww,
                                                    float* __restrict__ out, int N) {
    int b = blockIdx.x;
    int shard = b & 7;
    int node = (b >> 3) * 4 + (threadIdx.x >> 6);
    if (node >= N) return;
    int lane = threadIdx.x & 63;
    int c = shard * 64 + lane;

    float dn = dis[node];
    int e0 = offs[node], e1 = offs[node + 1];

    float acc;
    {
        unsigned short sv = hw[(size_t)node * HID + c];
        float g = __uint_as_float((unsigned)sv << 16);
        acc = g * dn * dn + bias[c];
    }

    for (int e = e0; e < e1; e += 8) {
        int idx[8]; float wgt[8];
#pragma unroll
        for (int j = 0; j < 8; ++j) {
            int ee = e + j;
            int ec = (ee < e1) ? ee : (e1 - 1);
            int2 rec = csr2[ec];
            idx[j] = rec.x;
            wgt[j] = (ee < e1) ? __int_as_float(rec.y) * dn : 0.f;
        }
        unsigned short v[8];
#pragma unroll
        for (int j = 0; j < 8; ++j)
            v[j] = hw[(size_t)idx[j] * HID + c];
#pragma unroll
        for (int j = 0; j < 8; ++j)
            acc += __uint_as_float((unsigned)v[j] << 16) * wgt[j];
    }

    float h = fmaxf(acc, 0.f);
    float po = h * Wo[c];
    float pw = h * Ww[c];
#pragma unroll
    for (int off = 32; off > 0; off >>= 1) {
        po += __shfl_down(po, off);
        pw += __shfl_down(pw, off);
    }
    if (lane == 0) {
        atomicAdd(&out[node], po);
        atomicAdd(&out[N + node], pw);
    }
}

// ---------------------------------------------------------------------------
extern "C" void kernel_launch(void* const* d_in, const int* in_sizes, int n_in,
                              void* d_out, int out_size, void* d_ws, size_t ws_size,
                              hipStream_t stream) {
    const float* x  = (const float*)d_in[0];
    const int*   ei = (const int*)d_in[1];
    const float* W1 = (const float*)d_in[2];
    const float* b1 = (const float*)d_in[3];
    const float* W2 = (const float*)d_in[4];
    const float* b2 = (const float*)d_in[5];
    const float* Wo = (const float*)d_in[6];
    const float* bo = (const float*)d_in[7];
    const float* Ww = (const float*)d_in[8];
    const float* bw = (const float*)d_in[9];

    const int N = in_sizes[0] / DIN;           // 25000
    const int E = in_sizes[1] / 2;             // 200000
    const int Mpad = (N + 127) & ~127;         // 25088
    const int Mtiles = Mpad / 128;             // 196
    const int nb = (N + 255) / 256;            // 98

    char* ws = (char*)d_ws;
    size_t p = 0;
    auto alloc = [&](size_t bytes) -> char* {
        char* r = ws + p;
        p += (bytes + 255) & ~(size_t)255;
        return r;
    };
    int*   cnt    = (int*)alloc((size_t)N * 4);
    int*   offs   = (int*)alloc((size_t)(N + 1) * 4);
    int*   cursor = (int*)alloc((size_t)N * 4);
    int*   tmp    = (int*)alloc((size_t)N * 4);
    int*   bsum   = (int*)alloc(132 * 4);
    float* dis    = (float*)alloc((size_t)N * 4);
    int2*  csr2   = (int2*)alloc((size_t)E * 8 + 64);
    unsigned short* Wt1 = (unsigned short*)alloc((size_t)512 * 512 * 2);
    unsigned short* Wt2 = (unsigned short*)alloc((size_t)512 * 512 * 2);
    unsigned short* hw  = (unsigned short*)alloc((size_t)Mpad * 512 * 2);
    unsigned short* h1  = (unsigned short*)alloc((size_t)Mpad * 512 * 2);

    const int* src = ei;
    const int* dst = ei + E;

    hipMemsetAsync(cnt, 0, (size_t)N * 4, stream);

    prelude<<<512 + (E + 255) / 256, 256, 0, stream>>>(W1, W2, Wt1, Wt2, dst, cnt, E);
    scan1<<<nb, 256, 0, stream>>>(cnt, tmp, bsum, N);
    scan2<<<1, 128, 0, stream>>>(bsum, nb);
    scan3<<<nb, 256, 0, stream>>>(cnt, tmp, bsum, offs, cursor, dis,
                                  (float*)d_out, bo, bw, N, nb);
    fill_kernel<<<(E + 255) / 256, 256, 0, stream>>>(src, dst, cursor, dis, csr2, E);

    const int ggrid = 8 * ((Mtiles + 7) / 8) * 4;   // 800 blocks, XCD-swizzled
    gemm_a32<<<ggrid, 256, 0, stream>>>(x, (const short*)Wt1, hw, N, Mtiles);
    agg_relu_sh<<<8 * ((Mpad + 3) / 4), 256, 0, stream>>>(hw, csr2, offs, dis, b1, h1, N, Mpad);
    gemm_bf16<<<ggrid, 256, 0, stream>>>((const short*)h1, (const short*)Wt2, hw, Mtiles);
    agg_heads_sh<<<8 * ((N + 3) / 4), 256, 0, stream>>>(hw, csr2, offs, dis, b2,
                                                        Wo, Ww, (float*)d_out, N);
}

// Round 6
// 245.275 us; speedup vs baseline: 1.5874x; 1.5874x over previous
//
#include <hip/hip_runtime.h>
#include <hip/hip_bf16.h>

#define DIN 512
#define HID 512

#define AS1 __attribute__((address_space(1)))
#define AS3 __attribute__((address_space(3)))

typedef __attribute__((ext_vector_type(8))) short bfrag;     // 8 bf16 (4 VGPRs)
typedef __attribute__((ext_vector_type(4))) float ffrag;     // 4 fp32 acc
typedef __attribute__((ext_vector_type(8))) unsigned short u16x8;
typedef __attribute__((ext_vector_type(4))) unsigned short u16x4;

// ---------------------------------------------------------------------------
// Prelude: transpose+cvt both weight matrices AND count incoming edges.
// ---------------------------------------------------------------------------
__global__ __launch_bounds__(256) void prelude(const float* __restrict__ W1,
                                               const float* __restrict__ W2,
                                               unsigned short* __restrict__ Wt1,
                                               unsigned short* __restrict__ Wt2,
                                               const int* __restrict__ dst,
                                               int* __restrict__ cnt, int E) {
    int b = blockIdx.x;
    if (b < 512) {
        int which = b >> 8;
        int bb = b & 255;
        const float* W = which ? W2 : W1;
        unsigned short* Wt = which ? Wt2 : Wt1;
        __shared__ float t[32][33];
        int tid = threadIdx.x;
        int tx = tid & 31, ty = tid >> 5;          // 32 x 8
        int n0 = (bb & 15) * 32, k0 = (bb >> 4) * 32;
#pragma unroll
        for (int s = 0; s < 4; ++s)
            t[ty + 8 * s][tx] = W[(size_t)(k0 + ty + 8 * s) * 512 + n0 + tx];
        __syncthreads();
#pragma unroll
        for (int s = 0; s < 4; ++s) {
            __hip_bfloat16 v = __float2bfloat16(t[tx][ty + 8 * s]);
            Wt[(size_t)(n0 + ty + 8 * s) * 512 + k0 + tx] = *(unsigned short*)&v;
        }
    } else {
        int e = (b - 512) * 256 + threadIdx.x;
        if (e < E) atomicAdd(&cnt[dst[e]], 1);
    }
}

// ---------------------------------------------------------------------------
// 3-stage scan
// ---------------------------------------------------------------------------
__global__ __launch_bounds__(256) void scan1(const int* __restrict__ cnt, int* __restrict__ tmp,
                                             int* __restrict__ bsum, int N) {
    int tid = threadIdx.x, lane = tid & 63, wave = tid >> 6;
    int i = blockIdx.x * 256 + tid;
    int v = (i < N) ? cnt[i] : 0;
    int incl = v;
#pragma unroll
    for (int o = 1; o < 64; o <<= 1) {
        int t = __shfl_up(incl, o);
        if (lane >= o) incl += t;
    }
    __shared__ int wtot[4];
    if (lane == 63) wtot[wave] = incl;
    __syncthreads();
    int woff = 0;
#pragma unroll
    for (int w = 0; w < 4; ++w) woff += (w < wave) ? wtot[w] : 0;
    if (i < N) tmp[i] = woff + incl - v;
    if (tid == 255) bsum[blockIdx.x] = woff + incl;
}

__global__ void scan2(int* __restrict__ bsum, int nb) {
    int tid = threadIdx.x;  // 128 threads, nb <= 128
    int lane = tid & 63, wave = tid >> 6;
    int v = (tid < nb) ? bsum[tid] : 0;
    int incl = v;
#pragma unroll
    for (int o = 1; o < 64; o <<= 1) {
        int t = __shfl_up(incl, o);
        if (lane >= o) incl += t;
    }
    __shared__ int w0;
    if (tid == 63) w0 = incl;
    __syncthreads();
    int off = wave ? w0 : 0;
    if (tid < nb) bsum[tid] = off + incl - v;
    if (tid == 127) bsum[nb] = off + incl;
}

// offs, cursor(=offs), dis, and d_out bias-init (heads atomicAdd onto it)
__global__ void scan3(const int* __restrict__ cnt, const int* __restrict__ tmp,
                      const int* __restrict__ bsum, int* __restrict__ offs,
                      int* __restrict__ cursor, float* __restrict__ dis,
                      float* __restrict__ out, const float* __restrict__ bo,
                      const float* __restrict__ bw, int N, int nb) {
    int i = blockIdx.x * 256 + threadIdx.x;
    if (i < N) {
        int o = tmp[i] + bsum[i >> 8];
        offs[i] = o;
        cursor[i] = o;
        dis[i] = rsqrtf((float)cnt[i] + 1.0f);
        out[i] = bo[0];
        out[N + i] = bw[0];
    }
    if (i == 0) offs[N] = bsum[nb];
}

// fill CSR as packed records {src, dis[src]}
__global__ void fill_kernel(const int* __restrict__ src, const int* __restrict__ dst,
                            int* __restrict__ cursor, const float* __restrict__ dis,
                            int2* __restrict__ csr2, int E) {
    int e = blockIdx.x * 256 + threadIdx.x;
    if (e >= E) return;
    int d = dst[e];
    int s = src[e];
    int pos = atomicAdd(&cursor[d], 1);
    int2 rec;
    rec.x = s;
    rec.y = __float_as_int(dis[s]);
    csr2[pos] = rec;
}

// ---------------------------------------------------------------------------
// XCD-swizzled tile mapping: b&7 = XCD; per-XCD index covers all 4 n-tiles of
// an m-tile consecutively so the A-tile stays in that XCD's L2.
// ---------------------------------------------------------------------------
__device__ inline bool tile_map(int b, int Mtiles, int& m0, int& n0) {
    int xcd = b & 7, i = b >> 3;
    int nt = i & 3, mg = i >> 2;
    int mt = mg * 8 + xcd;
    if (mt >= Mtiles) return false;
    m0 = mt * 128;
    n0 = nt * 128;
    return true;
}

__device__ inline bfrag pack8(float4 a, float4 b) {
    bfrag o;
    __hip_bfloat16 t;
    t = __float2bfloat16(a.x); o[0] = *(short*)&t;
    t = __float2bfloat16(a.y); o[1] = *(short*)&t;
    t = __float2bfloat16(a.z); o[2] = *(short*)&t;
    t = __float2bfloat16(a.w); o[3] = *(short*)&t;
    t = __float2bfloat16(b.x); o[4] = *(short*)&t;
    t = __float2bfloat16(b.y); o[5] = *(short*)&t;
    t = __float2bfloat16(b.z); o[6] = *(short*)&t;
    t = __float2bfloat16(b.w); o[7] = *(short*)&t;
    return o;
}

// Layer-1 GEMM: fp32 A staged to LDS, cvt at fragment read.
__global__ __launch_bounds__(256) void gemm_a32(const float* __restrict__ A,
                                                const short* __restrict__ B,
                                                unsigned short* __restrict__ C,
                                                int Nvalid, int Mtiles) {
    __shared__ __align__(16) float Asf[128 * 64];  // 32 KB fp32, XOR-16 chunks
    __shared__ __align__(16) short Bs[128 * 64];   // 16 KB bf16, XOR-8 chunks
    const int K = 512;
    int m0, n0;
    if (!tile_map(blockIdx.x, Mtiles, m0, n0)) return;
    int tid = threadIdx.x;
    int lane = tid & 63, wave = tid >> 6;
    int wm = (wave & 1) * 64;
    int wn = (wave >> 1) * 64;
    int r = lane & 15, q = lane >> 4;

    unsigned aoff[8]; int aldso[8];
#pragma unroll
    for (int i = 0; i < 8; ++i) {
        int s = i * 256 + tid;
        int row = s >> 4;
        int c = (s & 15) ^ (row & 15);
        int gr = m0 + row;
        if (gr > Nvalid - 1) gr = Nvalid - 1;
        aoff[i] = (unsigned)gr * K + c * 4;
        aldso[i] = (i * 256 + (tid & ~63)) * 4;
    }
    unsigned boff[4]; int bldso[4];
#pragma unroll
    for (int i = 0; i < 4; ++i) {
        int s = i * 256 + tid;
        int row = s >> 3;
        int c = (s & 7) ^ (row & 7);
        boff[i] = (unsigned)(n0 + row) * K + c * 8;
        bldso[i] = (i * 256 + (tid & ~63)) * 8;
    }

    ffrag acc[4][4];
#pragma unroll
    for (int i = 0; i < 4; ++i)
#pragma unroll
        for (int j = 0; j < 4; ++j) acc[i][j] = ffrag{0.f, 0.f, 0.f, 0.f};

    for (int k0 = 0; k0 < K; k0 += 64) {
#pragma unroll
        for (int i = 0; i < 8; ++i)
            __builtin_amdgcn_global_load_lds((const AS1 void*)(A + aoff[i] + k0),
                                             (AS3 void*)(Asf + aldso[i]), 16, 0, 0);
#pragma unroll
        for (int i = 0; i < 4; ++i)
            __builtin_amdgcn_global_load_lds((const AS1 void*)(B + boff[i] + k0),
                                             (AS3 void*)(Bs + bldso[i]), 16, 0, 0);
        __syncthreads();

#pragma unroll
        for (int s2 = 0; s2 < 2; ++s2) {
            bfrag af[4], bfr[4];
#pragma unroll
            for (int i = 0; i < 4; ++i) {
                int m = wm + i * 16 + r;
                int c0 = s2 * 8 + q * 2;
                int p0 = (c0 ^ (m & 15)) * 4;
                int p1 = ((c0 + 1) ^ (m & 15)) * 4;
                float4 f0 = *(const float4*)&Asf[m * 64 + p0];
                float4 f1 = *(const float4*)&Asf[m * 64 + p1];
                af[i] = pack8(f0, f1);
                int brow = wn + i * 16 + r;
                int bch = (s2 * 4 + q) ^ (brow & 7);
                bfr[i] = *(const bfrag*)&Bs[brow * 64 + bch * 8];
            }
#pragma unroll
            for (int i = 0; i < 4; ++i)
#pragma unroll
                for (int j = 0; j < 4; ++j)
                    acc[i][j] = __builtin_amdgcn_mfma_f32_16x16x32_bf16(bfr[j], af[i], acc[i][j], 0, 0, 0);
        }
        __syncthreads();
    }

#pragma unroll
    for (int i = 0; i < 4; ++i) {
        int m = m0 + wm + i * 16 + r;
#pragma unroll
        for (int j = 0; j < 4; ++j) {
            int n = n0 + wn + j * 16 + q * 4;
            u16x4 o;
#pragma unroll
            for (int reg = 0; reg < 4; ++reg) {
                __hip_bfloat16 v = __float2bfloat16(acc[i][j][reg]);
                o[reg] = *(unsigned short*)&v;
            }
            *(u16x4*)&C[(size_t)m * 512 + n] = o;
        }
    }
}

// Layer-2 GEMM (bf16 A), same swizzle.
__global__ __launch_bounds__(256) void gemm_bf16(const short* __restrict__ A,
                                                 const short* __restrict__ B,
                                                 unsigned short* __restrict__ C,
                                                 int Mtiles) {
    __shared__ __align__(16) short As[128 * 64];
    __shared__ __align__(16) short Bs[128 * 64];
    const int K = 512;
    int m0, n0;
    if (!tile_map(blockIdx.x, Mtiles, m0, n0)) return;
    int tid = threadIdx.x;
    int lane = tid & 63, wave = tid >> 6;
    int wm = (wave & 1) * 64;
    int wn = (wave >> 1) * 64;
    int r = lane & 15, q = lane >> 4;

    unsigned aoff[4], boff[4]; int ldso[4];
#pragma unroll
    for (int i = 0; i < 4; ++i) {
        int s = i * 256 + tid;
        int row = s >> 3;
        int c = (s & 7) ^ (row & 7);
        aoff[i] = (unsigned)(m0 + row) * K + c * 8;
        boff[i] = (unsigned)(n0 + row) * K + c * 8;
        ldso[i] = (i * 256 + (tid & ~63)) * 8;
    }

    ffrag acc[4][4];
#pragma unroll
    for (int i = 0; i < 4; ++i)
#pragma unroll
        for (int j = 0; j < 4; ++j) acc[i][j] = ffrag{0.f, 0.f, 0.f, 0.f};

    for (int k0 = 0; k0 < K; k0 += 64) {
#pragma unroll
        for (int i = 0; i < 4; ++i) {
            __builtin_amdgcn_global_load_lds((const AS1 void*)(A + aoff[i] + k0),
                                             (AS3 void*)(As + ldso[i]), 16, 0, 0);
            __builtin_amdgcn_global_load_lds((const AS1 void*)(B + boff[i] + k0),
                                             (AS3 void*)(Bs + ldso[i]), 16, 0, 0);
        }
        __syncthreads();

#pragma unroll
        for (int s2 = 0; s2 < 2; ++s2) {
            bfrag af[4], bfr[4];
#pragma unroll
            for (int i = 0; i < 4; ++i) {
                int arow = wm + i * 16 + r;
                int ach = (s2 * 4 + q) ^ (arow & 7);
                af[i] = *(const bfrag*)&As[arow * 64 + ach * 8];
                int brow = wn + i * 16 + r;
                int bch = (s2 * 4 + q) ^ (brow & 7);
                bfr[i] = *(const bfrag*)&Bs[brow * 64 + bch * 8];
            }
#pragma unroll
            for (int i = 0; i < 4; ++i)
#pragma unroll
                for (int j = 0; j < 4; ++j)
                    acc[i][j] = __builtin_amdgcn_mfma_f32_16x16x32_bf16(bfr[j], af[i], acc[i][j], 0, 0, 0);
        }
        __syncthreads();
    }

#pragma unroll
    for (int i = 0; i < 4; ++i) {
        int m = m0 + wm + i * 16 + r;
#pragma unroll
        for (int j = 0; j < 4; ++j) {
            int n = n0 + wn + j * 16 + q * 4;
            u16x4 o;
#pragma unroll
            for (int reg = 0; reg < 4; ++reg) {
                __hip_bfloat16 v = __float2bfloat16(acc[i][j][reg]);
                o[reg] = *(unsigned short*)&v;
            }
            *(u16x4*)&C[(size_t)m * 512 + n] = o;
        }
    }
}

// ---------------------------------------------------------------------------
// XCD-sharded aggregation v2: shard = blockIdx&7 (one XCD) covers 64 channels;
// per-XCD gather footprint 3.2 MB -> L2 resident.  Wave = 8 nodes, 8-lane
// cluster per node, each lane loads u16x8 (16 B) -> full vector efficiency.
// Batch-4 edge gathers for MLP.
// ---------------------------------------------------------------------------
__device__ inline void cvt8(u16x8 v, float* f) {
#pragma unroll
    for (int j = 0; j < 8; ++j) f[j] = __uint_as_float((unsigned)v[j] << 16);
}

__global__ __launch_bounds__(256) void agg_relu_sh(const unsigned short* __restrict__ hw,
                                                   const int2* __restrict__ csr2,
                                                   const int* __restrict__ offs,
                                                   const float* __restrict__ dis,
                                                   const float* __restrict__ bias,
                                                   unsigned short* __restrict__ out,
                                                   int N, int Mpad) {
    int b = blockIdx.x;
    int shard = b & 7;
    int tid = threadIdx.x;
    int wave = tid >> 6, lane = tid & 63;
    int cluster = lane >> 3;                       // node within wave
    int sub = lane & 7;                            // lane within cluster
    int node = (b >> 3) * 32 + wave * 8 + cluster;
    int c0 = shard * 64 + sub * 8;
    if (node >= N) {
        if (node < Mpad) {
            u16x8 z = {0, 0, 0, 0, 0, 0, 0, 0};
            *(u16x8*)&out[(size_t)node * HID + c0] = z;
        }
        return;
    }

    float dn = dis[node];
    int e0 = offs[node], e1 = offs[node + 1];

    float acc[8];
    {
        u16x8 sv = *(const u16x8*)&hw[(size_t)node * HID + c0];
        float g[8];
        cvt8(sv, g);
        float4 bb0 = *(const float4*)&bias[c0];
        float4 bb1 = *(const float4*)&bias[c0 + 4];
        float dis2 = dn * dn;
        acc[0] = g[0] * dis2 + bb0.x; acc[1] = g[1] * dis2 + bb0.y;
        acc[2] = g[2] * dis2 + bb0.z; acc[3] = g[3] * dis2 + bb0.w;
        acc[4] = g[4] * dis2 + bb1.x; acc[5] = g[5] * dis2 + bb1.y;
        acc[6] = g[6] * dis2 + bb1.z; acc[7] = g[7] * dis2 + bb1.w;
    }

    for (int e = e0; e < e1; e += 4) {
        int idx[4]; float wgt[4];
#pragma unroll
        for (int j = 0; j < 4; ++j) {
            int ee = e + j;
            int ec = (ee < e1) ? ee : (e1 - 1);
            int2 rec = csr2[ec];
            idx[j] = rec.x;
            wgt[j] = (ee < e1) ? __int_as_float(rec.y) * dn : 0.f;
        }
        u16x8 v[4];
#pragma unroll
        for (int j = 0; j < 4; ++j)
            v[j] = *(const u16x8*)&hw[(size_t)idx[j] * HID + c0];
#pragma unroll
        for (int j = 0; j < 4; ++j) {
            float g[8];
            cvt8(v[j], g);
#pragma unroll
            for (int t = 0; t < 8; ++t) acc[t] += g[t] * wgt[j];
        }
    }

    unsigned short o[8];
#pragma unroll
    for (int j = 0; j < 8; ++j) {
        __hip_bfloat16 v = __float2bfloat16(fmaxf(acc[j], 0.f));
        o[j] = *(unsigned short*)&v;
    }
    *(u16x8*)&out[(size_t)node * HID + c0] = *(u16x8*)o;
}

// Layer-2 sharded aggregation with fused heads: 8-ch in-lane dot, 8-lane
// cluster reduce, atomicAdd into bias-initialized d_out.
__global__ __launch_bounds__(256) void agg_heads_sh(const unsigned short* __restrict__ hw,
                                                    const int2* __restrict__ csr2,
                                                    const int* __restrict__ offs,
                                                    const float* __restrict__ dis,
                                                    const float* __restrict__ bias,
                                                    const float* __restrict__ Wo,
                                                    const float* __restrict__ Ww,
                                                    float* __restrict__ out, int N) {
    int b = blockIdx.x;
    int shard = b & 7;
    int tid = threadIdx.x;
    int wave = tid >> 6, lane = tid & 63;
    int cluster = lane >> 3;
    int sub = lane & 7;
    int node = (b >> 3) * 32 + wave * 8 + cluster;
    if (node >= N) return;
    int c0 = shard * 64 + sub * 8;

    float dn = dis[node];
    int e0 = offs[node], e1 = offs[node + 1];

    float acc[8];
    {
        u16x8 sv = *(const u16x8*)&hw[(size_t)node * HID + c0];
        float g[8];
        cvt8(sv, g);
        float4 bb0 = *(const float4*)&bias[c0];
        float4 bb1 = *(const float4*)&bias[c0 + 4];
        float dis2 = dn * dn;
        acc[0] = g[0] * dis2 + bb0.x; acc[1] = g[1] * dis2 + bb0.y;
        acc[2] = g[2] * dis2 + bb0.z; acc[3] = g[3] * dis2 + bb0.w;
        acc[4] = g[4] * dis2 + bb1.x; acc[5] = g[5] * dis2 + bb1.y;
        acc[6] = g[6] * dis2 + bb1.z; acc[7] = g[7] * dis2 + bb1.w;
    }

    for (int e = e0; e < e1; e += 4) {
        int idx[4]; float wgt[4];
#pragma unroll
        for (int j = 0; j < 4; ++j) {
            int ee = e + j;
            int ec = (ee < e1) ? ee : (e1 - 1);
            int2 rec = csr2[ec];
            idx[j] = rec.x;
            wgt[j] = (ee < e1) ? __int_as_float(rec.y) * dn : 0.f;
        }
        u16x8 v[4];
#pragma unroll
        for (int j = 0; j < 4; ++j)
            v[j] = *(const u16x8*)&hw[(size_t)idx[j] * HID + c0];
#pragma unroll
        for (int j = 0; j < 4; ++j) {
            float g[8];
            cvt8(v[j], g);
#pragma unroll
            for (int t = 0; t < 8; ++t) acc[t] += g[t] * wgt[j];
        }
    }

    float4 wo0 = *(const float4*)&Wo[c0];
    float4 wo1 = *(const float4*)&Wo[c0 + 4];
    float4 ww0 = *(const float4*)&Ww[c0];
    float4 ww1 = *(const float4*)&Ww[c0 + 4];
    float po = 0.f, pw = 0.f, h;
    h = fmaxf(acc[0], 0.f); po += h * wo0.x; pw += h * ww0.x;
    h = fmaxf(acc[1], 0.f); po += h * wo0.y; pw += h * ww0.y;
    h = fmaxf(acc[2], 0.f); po += h * wo0.z; pw += h * ww0.z;
    h = fmaxf(acc[3], 0.f); po += h * wo0.w; pw += h * ww0.w;
    h = fmaxf(acc[4], 0.f); po += h * wo1.x; pw += h * ww1.x;
    h = fmaxf(acc[5], 0.f); po += h * wo1.y; pw += h * ww1.y;
    h = fmaxf(acc[6], 0.f); po += h * wo1.z; pw += h * ww1.z;
    h = fmaxf(acc[7], 0.f); po += h * wo1.w; pw += h * ww1.w;

    // reduce across the 8-lane cluster (lanes are contiguous)
#pragma unroll
    for (int off = 4; off > 0; off >>= 1) {
        po += __shfl_down(po, off);
        pw += __shfl_down(pw, off);
    }
    if (sub == 0) {
        atomicAdd(&out[node], po);
        atomicAdd(&out[N + node], pw);
    }
}

// ---------------------------------------------------------------------------
extern "C" void kernel_launch(void* const* d_in, const int* in_sizes, int n_in,
                              void* d_out, int out_size, void* d_ws, size_t ws_size,
                              hipStream_t stream) {
    const float* x  = (const float*)d_in[0];
    const int*   ei = (const int*)d_in[1];
    const float* W1 = (const float*)d_in[2];
    const float* b1 = (const float*)d_in[3];
    const float* W2 = (const float*)d_in[4];
    const float* b2 = (const float*)d_in[5];
    const float* Wo = (const float*)d_in[6];
    const float* bo = (const float*)d_in[7];
    const float* Ww = (const float*)d_in[8];
    const float* bw = (const float*)d_in[9];

    const int N = in_sizes[0] / DIN;           // 25000
    const int E = in_sizes[1] / 2;             // 200000
    const int Mpad = (N + 127) & ~127;         // 25088 (multiple of 32)
    const int Mtiles = Mpad / 128;             // 196
    const int nb = (N + 255) / 256;            // 98

    char* ws = (char*)d_ws;
    size_t p = 0;
    auto alloc = [&](size_t bytes) -> char* {
        char* r = ws + p;
        p += (bytes + 255) & ~(size_t)255;
        return r;
    };
    int*   cnt    = (int*)alloc((size_t)N * 4);
    int*   offs   = (int*)alloc((size_t)(N + 1) * 4);
    int*   cursor = (int*)alloc((size_t)N * 4);
    int*   tmp    = (int*)alloc((size_t)N * 4);
    int*   bsum   = (int*)alloc(132 * 4);
    float* dis    = (float*)alloc((size_t)N * 4);
    int2*  csr2   = (int2*)alloc((size_t)E * 8 + 64);
    unsigned short* Wt1 = (unsigned short*)alloc((size_t)512 * 512 * 2);
    unsigned short* Wt2 = (unsigned short*)alloc((size_t)512 * 512 * 2);
    unsigned short* hw  = (unsigned short*)alloc((size_t)Mpad * 512 * 2);
    unsigned short* h1  = (unsigned short*)alloc((size_t)Mpad * 512 * 2);

    const int* src = ei;
    const int* dst = ei + E;

    hipMemsetAsync(cnt, 0, (size_t)N * 4, stream);

    prelude<<<512 + (E + 255) / 256, 256, 0, stream>>>(W1, W2, Wt1, Wt2, dst, cnt, E);
    scan1<<<nb, 256, 0, stream>>>(cnt, tmp, bsum, N);
    scan2<<<1, 128, 0, stream>>>(bsum, nb);
    scan3<<<nb, 256, 0, stream>>>(cnt, tmp, bsum, offs, cursor, dis,
                                  (float*)d_out, bo, bw, N, nb);
    fill_kernel<<<(E + 255) / 256, 256, 0, stream>>>(src, dst, cursor, dis, csr2, E);

    const int ggrid = 8 * ((Mtiles + 7) / 8) * 4;   // 800 blocks, XCD-swizzled
    gemm_a32<<<ggrid, 256, 0, stream>>>(x, (const short*)Wt1, hw, N, Mtiles);
    agg_relu_sh<<<8 * (Mpad / 32), 256, 0, stream>>>(hw, csr2, offs, dis, b1, h1, N, Mpad);
    gemm_bf16<<<ggrid, 256, 0, stream>>>((const short*)h1, (const short*)Wt2, hw, Mtiles);
    agg_heads_sh<<<8 * ((N + 31) / 32), 256, 0, stream>>>(hw, csr2, offs, dis, b2,
                                                          Wo, Ww, (float*)d_out, N);
}